// Round 2
// baseline (867.128 us; speedup 1.0000x reference)
//
#include <hip/hip_runtime.h>

typedef unsigned short u16;
typedef unsigned int u32;
typedef unsigned long long u64;

#define T_ 4
#define N_ 20000
#define E_ 640000
#define DIN 256
#define DOUT 128
#define NT (T_*N_)          // 80000
#define TE (T_*E_)          // 2560000
#define SLOPE 0.22916666666666666f

typedef __attribute__((ext_vector_type(8))) short short8;
typedef __attribute__((ext_vector_type(4))) float f32x4;

__device__ __forceinline__ float blo(u32 u) { return __uint_as_float(u << 16); }
__device__ __forceinline__ float bhi(u32 u) { return __uint_as_float(u & 0xFFFF0000u); }
__device__ __forceinline__ u16 f2bf(float f) {
    u32 u = __float_as_uint(f);
    return (u16)((u + 0x7FFFu + ((u >> 16) & 1u)) >> 16);
}
__device__ __forceinline__ u32 fkey(float f) {
    u32 u = __float_as_uint(f);
    return (u & 0x80000000u) ? ~u : (u | 0x80000000u);
}
__device__ __forceinline__ float fkeyinv(u32 k) {
    u32 u = (k & 0x80000000u) ? (k ^ 0x80000000u) : ~k;
    return __uint_as_float(u);
}

// ---------------- transpose+pack the 6 GRU weight matrices (f32 -> bf16 pairs) ------
// Tp[m][d2*256 + i] = pack(bf16(Wm[i][2*d2]), bf16(Wm[i][2*d2+1]))
__global__ void k_transpose(const float* Wz, const float* Uz, const float* Wr, const float* Ur,
                            const float* Wh, const float* Uh, u32* Tp) {
    int bid = blockIdx.x;
    int m = bid >> 7, b = bid & 127;
    int idx = b * 256 + threadIdx.x;      // 0..32767
    int d2 = idx & 127, i = idx >> 7;     // coalesced f32 pair reads
    const float* src;
    switch (m) {
        case 0: src = Wz; break;
        case 1: src = Uz; break;
        case 2: src = Wr; break;
        case 3: src = Ur; break;
        case 4: src = Wh; break;
        default: src = Uh; break;
    }
    float lo = src[i * 256 + 2 * d2];
    float hi = src[i * 256 + 2 * d2 + 1];
    Tp[m * 32768 + d2 * 256 + i] = (u32)f2bf(lo) | ((u32)f2bf(hi) << 16);
}

// ---------------- scores: (x.p)/||p|| + mask, plus x -> bf16 conversion ----------------
__global__ __launch_bounds__(256) void k_scores(const float* x, const float* p, const float* mask,
                                                float* scores, u16* xb16) {
    __shared__ float pl[256];
    __shared__ float s_invn;
    int tid = threadIdx.x;
    pl[tid] = p[tid];
    __syncthreads();
    if (tid < 64) {
        float v = pl[tid] * pl[tid] + pl[tid + 64] * pl[tid + 64] +
                  pl[tid + 128] * pl[tid + 128] + pl[tid + 192] * pl[tid + 192];
        for (int o = 32; o > 0; o >>= 1) v += __shfl_xor(v, o);
        if (tid == 0) s_invn = 1.0f / sqrtf(v);
    }
    __syncthreads();
    int wid = tid >> 6, lane = tid & 63;
    for (int it = 0; it < 4; ++it) {
        int node = blockIdx.x * 16 + wid * 4 + it;   // 5000*16 == 80000
        const float* row = x + (size_t)node * DIN + lane * 4;
        float4 u = *(const float4*)row;
        float d = u.x * pl[lane * 4 + 0] + u.y * pl[lane * 4 + 1] +
                  u.z * pl[lane * 4 + 2] + u.w * pl[lane * 4 + 3];
        u32 p0 = (u32)f2bf(u.x) | ((u32)f2bf(u.y) << 16);
        u32 p1 = (u32)f2bf(u.z) | ((u32)f2bf(u.w) << 16);
        *(uint2*)(xb16 + (size_t)node * DIN + lane * 4) = make_uint2(p0, p1);
        for (int o = 32; o > 0; o >>= 1) d += __shfl_xor(d, o);
        if (lane == 0) scores[node] = d * s_invn + mask[node];
    }
}

// ---------------- CSR build ----------------
__global__ void k_count(const int* ei, int* counts) {
    int e = blockIdx.x * 256 + threadIdx.x;          // < TE exactly
    int t = e / E_;
    int l = e - t * E_;
    int dst = ei[t * (2 * E_) + l];
    atomicAdd(&counts[t * N_ + dst], 1);
}

__global__ __launch_bounds__(256) void k_scan1(const int* counts, int* offsets, int* blkSum) {
    int tid = threadIdx.x;
    int i = blockIdx.x * 256 + tid;
    int v = (i < NT) ? counts[i] : 0;
    int lane = tid & 63, wid = tid >> 6;
    int x = v;
    for (int o = 1; o < 64; o <<= 1) {
        int y = __shfl_up(x, o);
        if (lane >= o) x += y;
    }
    __shared__ int wtot[4];
    if (lane == 63) wtot[wid] = x;
    __syncthreads();
    int wpre = 0;
    for (int w = 0; w < wid; ++w) wpre += wtot[w];
    if (i < NT) offsets[i] = wpre + x - v;
    if (tid == 255) blkSum[blockIdx.x] = wpre + x;
}

__global__ void k_scan2(const int* blkSum, int* blkOff, int* offsets) {
    int lane = threadIdx.x;   // 64 threads, 1 wave
    int carry = 0;
    for (int base = 0; base < 313; base += 64) {
        int id = base + lane;
        int v = (id < 313) ? blkSum[id] : 0;
        int x = v;
        for (int o = 1; o < 64; o <<= 1) {
            int y = __shfl_up(x, o);
            if (lane >= o) x += y;
        }
        if (id < 313) blkOff[id] = carry + x - v;
        carry += __shfl(x, 63);
    }
    if (lane == 0) offsets[NT] = carry;   // == TE
}

__global__ void k_scan3(int* offsets, const int* blkOff) {
    int i = blockIdx.x * 256 + threadIdx.x;
    if (i < NT) offsets[i] += blkOff[blockIdx.x];
}

__global__ void k_place(const int* ei, const float* ew, const int* offsets, int* cursor,
                        uint2* srcw) {
    int e = blockIdx.x * 256 + threadIdx.x;          // < TE exactly
    int t = e / E_;
    int l = e - t * E_;
    int dst = ei[t * (2 * E_) + l];
    int src = ei[t * (2 * E_) + E_ + l];
    float wv = ew[t * E_ + l];
    int g = t * N_ + dst;
    int pos = atomicAdd(&cursor[g], 1);
    srcw[offsets[g] + pos] = make_uint2((u32)(t * N_ + src), __float_as_uint(wv));
}

// ---------------- top-128 (radix select, exact jax order) + xtT build ----------------
// xtT layout: [j=128][d=256], xtT[j][d] = x[idx[j]][d] * tanh(val[j])
__global__ __launch_bounds__(256) void k_topk(const float* scores, const float* x, float* xtT) {
    int t = blockIdx.x;
    int tid = threadIdx.x;
    const float* sc = scores + t * N_;
    __shared__ u32 hist[256];
    __shared__ u32 sh_dig, sh_need;
    __shared__ u64 sel[256];
    __shared__ u32 selCount;
    __shared__ u32 idxl[128];
    __shared__ float tvl[128];

    u32 pref = 0;
    u32 need = 128;
    for (int pass = 0; pass < 4; ++pass) {
        int shift = 24 - 8 * pass;
        hist[tid] = 0;
        __syncthreads();
        for (int i = tid; i < N_; i += 256) {
            u32 k = fkey(sc[i]);
            bool ok = (pass == 0) || ((k >> (shift + 8)) == pref);
            if (ok) atomicAdd(&hist[(k >> shift) & 255u], 1u);
        }
        __syncthreads();
        if (tid < 64) {
            int l = tid;
            u32 s = hist[4 * l] + hist[4 * l + 1] + hist[4 * l + 2] + hist[4 * l + 3];
            u32 S = s;
            for (int o = 1; o < 64; o <<= 1) {
                u32 y = __shfl_down(S, o);
                if (l + o < 64) S += y;
            }
            u64 m = __ballot(S >= need);
            int L = 63 - __builtin_clzll(m);
            if (l == L) {
                u32 Snext = S - s;
                u32 r = 0;
                for (int dd = 3; dd >= 0; --dd) {
                    u32 hb = hist[4 * L + dd];
                    r += hb;
                    if (Snext + r >= need) {
                        sh_dig = (u32)(4 * L + dd);
                        sh_need = need - (Snext + r - hb);
                        break;
                    }
                }
            }
        }
        __syncthreads();
        pref = (pref << 8) | sh_dig;
        need = sh_need;
        __syncthreads();
    }
    if (tid == 0) selCount = 0;
    __syncthreads();
    u32 theta = pref;
    for (int i = tid; i < N_; i += 256) {
        u32 k = fkey(sc[i]);
        if (k >= theta) {
            u32 pos = atomicAdd(&selCount, 1u);
            if (pos < 256) sel[pos] = (((u64)(k ^ 0xFFFFFFFFu)) << 32) | (u32)i;
        }
    }
    __syncthreads();
    u32 c = selCount;
    if (c > 256) c = 256;
    if ((u32)tid >= c) sel[tid] = 0xFFFFFFFFFFFFFFFFull;
    __syncthreads();
    // bitonic ascending sort: key = (~fkey)<<32 | idx  -> value desc, idx asc
    for (int k2 = 2; k2 <= 256; k2 <<= 1) {
        for (int jj = k2 >> 1; jj > 0; jj >>= 1) {
            int i = tid, ixj = i ^ jj;
            if (ixj > i) {
                u64 A = sel[i], B = sel[ixj];
                bool asc = ((i & k2) == 0);
                bool sw = asc ? (A > B) : (A < B);
                if (sw) { sel[i] = B; sel[ixj] = A; }
            }
            __syncthreads();
        }
    }
    if (tid < 128) {
        u64 v = sel[tid];
        u32 k = ((u32)(v >> 32)) ^ 0xFFFFFFFFu;
        idxl[tid] = (u32)(v & 0xFFFFFFFFu);
        tvl[tid] = tanhf(fkeyinv(k));
    }
    __syncthreads();
    float* xt_t = xtT + t * (DIN * DOUT);
    const float* xb = x + (size_t)t * N_ * DIN;
    for (int e2 = tid; e2 < DIN * DOUT; e2 += 256) {
        int j = e2 >> 8, d = e2 & 255;
        xt_t[e2] = xb[(size_t)idxl[j] * DIN + d] * tvl[j];
    }
}

// ---------------- fused matrix-GRU: one block per 2 output columns (j0, j0+64) -------
// State layout: WT[j=128][i=256] f32.  Also emits bf16 WnT[j][i] for the GEMM B operand.
__global__ __launch_bounds__(256) void k_gru(const float* xtT, const float* WprevT,
                                             const float* W0, int firstT, const u32* Tp,
                                             const float* bz, const float* br, const float* bh,
                                             float* WnextT, u16* WnT_t) {
    int j0 = blockIdx.x;          // 0..63
    int j1 = j0 + 64;
    int i = threadIdx.x;          // 0..255
    __shared__ float sxt[2][256], sW[2][256], srw[2][256];
    sxt[0][i] = xtT[j0 * 256 + i];
    sxt[1][i] = xtT[j1 * 256 + i];
    float wv0 = firstT ? W0[i * 128 + j0] : WprevT[j0 * 256 + i];
    float wv1 = firstT ? W0[i * 128 + j1] : WprevT[j1 * 256 + i];
    sW[0][i] = wv0;
    sW[1][i] = wv1;
    __syncthreads();
    const u32* WzT = Tp;
    const u32* UzT = Tp + 32768;
    const u32* WrT = Tp + 65536;
    const u32* UrT = Tp + 98304;
    const u32* WhT = Tp + 131072;
    const u32* UhT = Tp + 163840;
    float az0 = bz[i * 128 + j0], az1 = bz[i * 128 + j1];
    float ar0 = br[i * 128 + j0], ar1 = br[i * 128 + j1];
#pragma unroll 4
    for (int d2 = 0; d2 < 128; ++d2) {
        float x00 = sxt[0][2 * d2], x01 = sxt[0][2 * d2 + 1];
        float x10 = sxt[1][2 * d2], x11 = sxt[1][2 * d2 + 1];
        float w00 = sW[0][2 * d2], w01 = sW[0][2 * d2 + 1];
        float w10 = sW[1][2 * d2], w11 = sW[1][2 * d2 + 1];
        u32 a = WzT[d2 * 256 + i], b = UzT[d2 * 256 + i];
        u32 cc = WrT[d2 * 256 + i], dd = UrT[d2 * 256 + i];
        az0 += blo(a) * x00 + bhi(a) * x01 + blo(b) * w00 + bhi(b) * w01;
        az1 += blo(a) * x10 + bhi(a) * x11 + blo(b) * w10 + bhi(b) * w11;
        ar0 += blo(cc) * x00 + bhi(cc) * x01 + blo(dd) * w00 + bhi(dd) * w01;
        ar1 += blo(cc) * x10 + bhi(cc) * x11 + blo(dd) * w10 + bhi(dd) * w11;
    }
    float z0 = 1.0f / (1.0f + expf(-az0));
    float z1 = 1.0f / (1.0f + expf(-az1));
    float r0 = 1.0f / (1.0f + expf(-ar0));
    float r1 = 1.0f / (1.0f + expf(-ar1));
    srw[0][i] = r0 * wv0;
    srw[1][i] = r1 * wv1;
    __syncthreads();
    float ah0 = bh[i * 128 + j0], ah1 = bh[i * 128 + j1];
#pragma unroll 4
    for (int d2 = 0; d2 < 128; ++d2) {
        float x00 = sxt[0][2 * d2], x01 = sxt[0][2 * d2 + 1];
        float x10 = sxt[1][2 * d2], x11 = sxt[1][2 * d2 + 1];
        float r00 = srw[0][2 * d2], r01 = srw[0][2 * d2 + 1];
        float r10 = srw[1][2 * d2], r11 = srw[1][2 * d2 + 1];
        u32 a = WhT[d2 * 256 + i], b = UhT[d2 * 256 + i];
        ah0 += blo(a) * x00 + bhi(a) * x01 + blo(b) * r00 + bhi(b) * r01;
        ah1 += blo(a) * x10 + bhi(a) * x11 + blo(b) * r10 + bhi(b) * r11;
    }
    float h0 = tanhf(ah0), h1 = tanhf(ah1);
    float wn0 = (1.0f - z0) * wv0 + z0 * h0;
    float wn1 = (1.0f - z1) * wv1 + z1 * h1;
    WnextT[j0 * 256 + i] = wn0;
    WnextT[j1 * 256 + i] = wn1;
    WnT_t[j0 * 256 + i] = f2bf(wn0);
    WnT_t[j1 * 256 + i] = f2bf(wn1);
}

// ---------------- y = x_bf16 @ Wn (MFMA bf16), batched over t ----------------
__global__ __launch_bounds__(128) void k_gemm(const u16* xb16, const u16* WnT, u16* y) {
    int t = blockIdx.y;
    const u16* xb = xb16 + (size_t)t * N_ * DIN;
    const u16* Bt = WnT + t * (DIN * DOUT);
    u16* yb = y + (size_t)t * N_ * DOUT;
    int wid = threadIdx.x >> 6, lane = threadIdx.x & 63;
    int quad = lane >> 4, lm = lane & 15;
    int rowBase = blockIdx.x * 64 + wid * 32;
    f32x4 acc[2][8];
#pragma unroll
    for (int mi = 0; mi < 2; ++mi)
#pragma unroll
        for (int ni = 0; ni < 8; ++ni) acc[mi][ni] = (f32x4){0.f, 0.f, 0.f, 0.f};
    size_t aoff[2];
#pragma unroll
    for (int mi = 0; mi < 2; ++mi) {
        int r = rowBase + mi * 16 + lm;
        if (r > N_ - 1) r = N_ - 1;
        aoff[mi] = (size_t)r * DIN + quad * 8;
    }
    const u16* bbase = Bt + lm * 256 + quad * 8;
    for (int kk = 0; kk < 256; kk += 32) {
        short8 a0 = *(const short8*)(xb + aoff[0] + kk);
        short8 a1 = *(const short8*)(xb + aoff[1] + kk);
#pragma unroll
        for (int ni = 0; ni < 8; ++ni) {
            short8 b = *(const short8*)(bbase + ni * 4096 + kk);
            acc[0][ni] = __builtin_amdgcn_mfma_f32_16x16x32_bf16(a0, b, acc[0][ni], 0, 0, 0);
            acc[1][ni] = __builtin_amdgcn_mfma_f32_16x16x32_bf16(a1, b, acc[1][ni], 0, 0, 0);
        }
    }
#pragma unroll
    for (int mi = 0; mi < 2; ++mi)
#pragma unroll
        for (int ni = 0; ni < 8; ++ni)
#pragma unroll
            for (int r = 0; r < 4; ++r) {
                int row = rowBase + mi * 16 + quad * 4 + r;
                if (row < N_) yb[(size_t)row * DOUT + ni * 16 + lm] = f2bf(acc[mi][ni][r]);
            }
}

// ---------------- CSR gather-aggregate + RReLU + f32 store ----------------
__global__ __launch_bounds__(256) void k_agg(const int* offsets, const uint2* srcw,
                                             const u16* y, float* out) {
    int g = blockIdx.x * 4 + (threadIdx.x >> 6);   // < NT
    int lane = threadIdx.x & 63;
    int o0 = offsets[g], o1 = offsets[g + 1];
    float a0 = 0.f, a1 = 0.f;
    for (int e = o0; e < o1; ++e) {
        uint2 m = srcw[e];
        float wv = __uint_as_float(m.y);
        u32 yv = *(const u32*)(y + (size_t)m.x * DOUT + lane * 2);
        a0 += wv * blo(yv);
        a1 += wv * bhi(yv);
    }
    a0 = (a0 >= 0.f) ? a0 : SLOPE * a0;
    a1 = (a1 >= 0.f) ? a1 : SLOPE * a1;
    float2 o2 = make_float2(a0, a1);
    *(float2*)(out + (size_t)g * DOUT + lane * 2) = o2;
}

extern "C" void kernel_launch(void* const* d_in, const int* in_sizes, int n_in,
                              void* d_out, int out_size, void* d_ws, size_t ws_size,
                              hipStream_t stream) {
    const float* x = (const float*)d_in[0];
    const int* ei = (const int*)d_in[1];
    const float* ew = (const float*)d_in[2];
    const float* mask = (const float*)d_in[3];
    const float* p = (const float*)d_in[4];
    const float* Wz = (const float*)d_in[5];
    const float* Uz = (const float*)d_in[6];
    const float* bz = (const float*)d_in[7];
    const float* Wr = (const float*)d_in[8];
    const float* Ur = (const float*)d_in[9];
    const float* br = (const float*)d_in[10];
    const float* Wh = (const float*)d_in[11];
    const float* Uh = (const float*)d_in[12];
    const float* bh = (const float*)d_in[13];
    const float* W0 = (const float*)d_in[14];
    float* out = (float*)d_out;

    char* w = (char*)d_ws;
    u16* xb16 = (u16*)w;        w += (size_t)NT * DIN * 2;   // 40,960,000
    float* scores = (float*)w;  w += 320256;                 // NT f32
    float* xtT = (float*)w;     w += 4 * 32768 * 4;          // [t][128][256] f32
    float* Wst = (float*)w;     w += 2 * 32768 * 4;          // ping-pong W^T state f32
    u16* WnT = (u16*)w;         w += 4 * 32768 * 2;          // [t][128][256] bf16
    u32* Tp = (u32*)w;          w += 6 * 32768 * 4;          // packed transposed weights
    u16* y = (u16*)w;           w += (size_t)NT * DOUT * 2;  // [t][N][128] bf16
    int* counts = (int*)w;      w += 320000;
    int* cursor = (int*)w;      w += 320000;                 // adjacent to counts
    int* offsets = (int*)w;     w += 320256;                 // NT+1
    int* blkSum = (int*)w;      w += 2048;
    int* blkOff = (int*)w;      w += 2048;
    uint2* srcw = (uint2*)w;    w += (size_t)TE * 8;

    hipMemsetAsync(counts, 0, 640000, stream);  // counts + cursor

    k_transpose<<<768, 256, 0, stream>>>(Wz, Uz, Wr, Ur, Wh, Uh, Tp);
    k_scores<<<5000, 256, 0, stream>>>(x, p, mask, scores, xb16);
    k_count<<<TE / 256, 256, 0, stream>>>(ei, counts);
    k_scan1<<<313, 256, 0, stream>>>(counts, offsets, blkSum);
    k_scan2<<<1, 64, 0, stream>>>(blkSum, blkOff, offsets);
    k_scan3<<<313, 256, 0, stream>>>(offsets, blkOff);
    k_place<<<TE / 256, 256, 0, stream>>>(ei, ew, offsets, cursor, srcw);
    k_topk<<<4, 256, 0, stream>>>(scores, x, xtT);

    for (int t = 0; t < 4; ++t) {
        const float* WprevT = (t == 0) ? Wst : (Wst + ((t + 1) & 1) * 32768);
        float* WnextT = Wst + (t & 1) * 32768;
        k_gru<<<64, 256, 0, stream>>>(xtT + t * 32768, WprevT, W0, (t == 0) ? 1 : 0, Tp,
                                      bz, br, bh, WnextT, WnT + t * 32768);
    }
    k_gemm<<<dim3(313, 4), 128, 0, stream>>>(xb16, WnT, y);
    k_agg<<<N_, 256, 0, stream>>>(offsets, srcw, y, out);
}

// Round 3
// 664.639 us; speedup vs baseline: 1.3047x; 1.3047x over previous
//
#include <hip/hip_runtime.h>

typedef unsigned short u16;
typedef unsigned int u32;
typedef unsigned long long u64;

#define T_ 4
#define N_ 20000
#define E_ 640000
#define DIN 256
#define DOUT 128
#define NT (T_*N_)          // 80000
#define TE (T_*E_)          // 2560000
#define SLOPE 0.22916666666666666f

typedef __attribute__((ext_vector_type(8))) short short8;
typedef __attribute__((ext_vector_type(4))) float f32x4;

__device__ __forceinline__ float blo(u32 u) { return __uint_as_float(u << 16); }
__device__ __forceinline__ float bhi(u32 u) { return __uint_as_float(u & 0xFFFF0000u); }
__device__ __forceinline__ u16 f2bf(float f) {
    u32 u = __float_as_uint(f);
    return (u16)((u + 0x7FFFu + ((u >> 16) & 1u)) >> 16);
}
__device__ __forceinline__ u32 fkey(float f) {
    u32 u = __float_as_uint(f);
    return (u & 0x80000000u) ? ~u : (u | 0x80000000u);
}
__device__ __forceinline__ float fkeyinv(u32 k) {
    u32 u = (k & 0x80000000u) ? (k ^ 0x80000000u) : ~k;
    return __uint_as_float(u);
}

// ---------------- transpose+pack the 6 GRU weight matrices (f32 -> bf16 pairs) ------
__global__ void k_transpose(const float* Wz, const float* Uz, const float* Wr, const float* Ur,
                            const float* Wh, const float* Uh, u32* Tp) {
    int bid = blockIdx.x;
    int m = bid >> 7, b = bid & 127;
    int idx = b * 256 + threadIdx.x;      // 0..32767
    int d2 = idx & 127, i = idx >> 7;     // coalesced f32 pair reads
    const float* src;
    switch (m) {
        case 0: src = Wz; break;
        case 1: src = Uz; break;
        case 2: src = Wr; break;
        case 3: src = Ur; break;
        case 4: src = Wh; break;
        default: src = Uh; break;
    }
    float lo = src[i * 256 + 2 * d2];
    float hi = src[i * 256 + 2 * d2 + 1];
    Tp[m * 32768 + d2 * 256 + i] = (u32)f2bf(lo) | ((u32)f2bf(hi) << 16);
}

// ---------------- scores: (x.p)/||p|| + mask, plus x -> bf16 conversion ----------------
__global__ __launch_bounds__(256) void k_scores(const float* x, const float* p, const float* mask,
                                                float* scores, u16* xb16) {
    __shared__ float pl[256];
    __shared__ float s_invn;
    int tid = threadIdx.x;
    pl[tid] = p[tid];
    __syncthreads();
    if (tid < 64) {
        float v = pl[tid] * pl[tid] + pl[tid + 64] * pl[tid + 64] +
                  pl[tid + 128] * pl[tid + 128] + pl[tid + 192] * pl[tid + 192];
        for (int o = 32; o > 0; o >>= 1) v += __shfl_xor(v, o);
        if (tid == 0) s_invn = 1.0f / sqrtf(v);
    }
    __syncthreads();
    int wid = tid >> 6, lane = tid & 63;
    for (int it = 0; it < 4; ++it) {
        int node = blockIdx.x * 16 + wid * 4 + it;   // 5000*16 == 80000
        const float* row = x + (size_t)node * DIN + lane * 4;
        float4 u = *(const float4*)row;
        float d = u.x * pl[lane * 4 + 0] + u.y * pl[lane * 4 + 1] +
                  u.z * pl[lane * 4 + 2] + u.w * pl[lane * 4 + 3];
        u32 p0 = (u32)f2bf(u.x) | ((u32)f2bf(u.y) << 16);
        u32 p1 = (u32)f2bf(u.z) | ((u32)f2bf(u.w) << 16);
        *(uint2*)(xb16 + (size_t)node * DIN + lane * 4) = make_uint2(p0, p1);
        for (int o = 32; o > 0; o >>= 1) d += __shfl_xor(d, o);
        if (lane == 0) scores[node] = d * s_invn + mask[node];
    }
}

// ---------------- CSR build ----------------
__global__ void k_count(const int* ei, int* counts) {
    int e = blockIdx.x * 256 + threadIdx.x;          // < TE exactly
    int t = e / E_;
    int l = e - t * E_;
    int dst = ei[t * (2 * E_) + l];
    atomicAdd(&counts[t * N_ + dst], 1);
}

__global__ __launch_bounds__(256) void k_scan1(const int* counts, int* offsets, int* blkSum) {
    int tid = threadIdx.x;
    int i = blockIdx.x * 256 + tid;
    int v = (i < NT) ? counts[i] : 0;
    int lane = tid & 63, wid = tid >> 6;
    int x = v;
    for (int o = 1; o < 64; o <<= 1) {
        int y = __shfl_up(x, o);
        if (lane >= o) x += y;
    }
    __shared__ int wtot[4];
    if (lane == 63) wtot[wid] = x;
    __syncthreads();
    int wpre = 0;
    for (int w = 0; w < wid; ++w) wpre += wtot[w];
    if (i < NT) offsets[i] = wpre + x - v;
    if (tid == 255) blkSum[blockIdx.x] = wpre + x;
}

__global__ void k_scan2(const int* blkSum, int* blkOff, int* offsets) {
    int lane = threadIdx.x;   // 64 threads, 1 wave
    int carry = 0;
    for (int base = 0; base < 313; base += 64) {
        int id = base + lane;
        int v = (id < 313) ? blkSum[id] : 0;
        int x = v;
        for (int o = 1; o < 64; o <<= 1) {
            int y = __shfl_up(x, o);
            if (lane >= o) x += y;
        }
        if (id < 313) blkOff[id] = carry + x - v;
        carry += __shfl(x, 63);
    }
    if (lane == 0) offsets[NT] = carry;   // == TE
}

__global__ void k_scan3(int* offsets, const int* blkOff) {
    int i = blockIdx.x * 256 + threadIdx.x;
    if (i < NT) offsets[i] += blkOff[blockIdx.x];
}

__global__ void k_place(const int* ei, const float* ew, const int* offsets, int* cursor,
                        uint2* srcw) {
    int e = blockIdx.x * 256 + threadIdx.x;          // < TE exactly
    int t = e / E_;
    int l = e - t * E_;
    int dst = ei[t * (2 * E_) + l];
    int src = ei[t * (2 * E_) + E_ + l];
    float wv = ew[t * E_ + l];
    int g = t * N_ + dst;
    int pos = atomicAdd(&cursor[g], 1);
    srcw[offsets[g] + pos] = make_uint2((u32)(t * N_ + src), __float_as_uint(wv));
}

// ---------------- top-128 (radix select, exact jax order) + xtT build ----------------
// xtT layout: [j=128][d=256], xtT[j][d] = x[idx[j]][d] * tanh(val[j])
__global__ __launch_bounds__(1024) void k_topk(const float* scores, const float* x, float* xtT) {
    int t = blockIdx.x;
    int tid = threadIdx.x;   // 0..1023
    const float* sc = scores + t * N_;
    __shared__ u32 hist[256];
    __shared__ u32 sh_dig, sh_need;
    __shared__ u64 sel[256];
    __shared__ u32 selCount;
    __shared__ u32 idxl[128];
    __shared__ float tvl[128];

    u32 pref = 0;
    u32 need = 128;
    for (int pass = 0; pass < 4; ++pass) {
        int shift = 24 - 8 * pass;
        if (tid < 256) hist[tid] = 0;
        __syncthreads();
        for (int i = tid; i < N_; i += 1024) {
            u32 k = fkey(sc[i]);
            bool ok = (pass == 0) || ((k >> (shift + 8)) == pref);
            if (ok) atomicAdd(&hist[(k >> shift) & 255u], 1u);
        }
        __syncthreads();
        if (tid < 64) {
            int l = tid;
            u32 s = hist[4 * l] + hist[4 * l + 1] + hist[4 * l + 2] + hist[4 * l + 3];
            u32 S = s;
            for (int o = 1; o < 64; o <<= 1) {
                u32 y = __shfl_down(S, o);
                if (l + o < 64) S += y;
            }
            u64 m = __ballot(S >= need);
            int L = 63 - __builtin_clzll(m);
            if (l == L) {
                u32 Snext = S - s;
                u32 r = 0;
                for (int dd = 3; dd >= 0; --dd) {
                    u32 hb = hist[4 * L + dd];
                    r += hb;
                    if (Snext + r >= need) {
                        sh_dig = (u32)(4 * L + dd);
                        sh_need = need - (Snext + r - hb);
                        break;
                    }
                }
            }
        }
        __syncthreads();
        pref = (pref << 8) | sh_dig;
        need = sh_need;
        __syncthreads();
    }
    if (tid == 0) selCount = 0;
    __syncthreads();
    u32 theta = pref;
    for (int i = tid; i < N_; i += 1024) {
        u32 k = fkey(sc[i]);
        if (k >= theta) {
            u32 pos = atomicAdd(&selCount, 1u);
            if (pos < 256) sel[pos] = (((u64)(k ^ 0xFFFFFFFFu)) << 32) | (u32)i;
        }
    }
    __syncthreads();
    u32 c = selCount;
    if (c > 256) c = 256;
    if (tid < 256 && (u32)tid >= c) sel[tid] = 0xFFFFFFFFFFFFFFFFull;
    __syncthreads();
    // bitonic ascending sort: key = (~fkey)<<32 | idx  -> value desc, idx asc
    for (int k2 = 2; k2 <= 256; k2 <<= 1) {
        for (int jj = k2 >> 1; jj > 0; jj >>= 1) {
            if (tid < 256) {
                int i = tid, ixj = i ^ jj;
                if (ixj > i) {
                    u64 A = sel[i], B = sel[ixj];
                    bool asc = ((i & k2) == 0);
                    bool sw = asc ? (A > B) : (A < B);
                    if (sw) { sel[i] = B; sel[ixj] = A; }
                }
            }
            __syncthreads();
        }
    }
    if (tid < 128) {
        u64 v = sel[tid];
        u32 k = ((u32)(v >> 32)) ^ 0xFFFFFFFFu;
        idxl[tid] = (u32)(v & 0xFFFFFFFFu);
        tvl[tid] = tanhf(fkeyinv(k));
    }
    __syncthreads();
    float* xt_t = xtT + t * (DIN * DOUT);
    const float* xb = x + (size_t)t * N_ * DIN;
    for (int e2 = tid; e2 < DIN * DOUT; e2 += 1024) {
        int j = e2 >> 8, d = e2 & 255;
        xt_t[e2] = xb[(size_t)idxl[j] * DIN + d] * tvl[j];
    }
}

// ---------------- fused matrix-GRU: one block per 2 output columns (j0, j0+64) -------
__global__ __launch_bounds__(256) void k_gru(const float* xtT, const float* WprevT,
                                             const float* W0, int firstT, const u32* Tp,
                                             const float* bz, const float* br, const float* bh,
                                             float* WnextT, u16* WnT_t) {
    int j0 = blockIdx.x;          // 0..63
    int j1 = j0 + 64;
    int i = threadIdx.x;          // 0..255
    __shared__ float sxt[2][256], sW[2][256], srw[2][256];
    sxt[0][i] = xtT[j0 * 256 + i];
    sxt[1][i] = xtT[j1 * 256 + i];
    float wv0 = firstT ? W0[i * 128 + j0] : WprevT[j0 * 256 + i];
    float wv1 = firstT ? W0[i * 128 + j1] : WprevT[j1 * 256 + i];
    sW[0][i] = wv0;
    sW[1][i] = wv1;
    __syncthreads();
    const u32* WzT = Tp;
    const u32* UzT = Tp + 32768;
    const u32* WrT = Tp + 65536;
    const u32* UrT = Tp + 98304;
    const u32* WhT = Tp + 131072;
    const u32* UhT = Tp + 163840;
    float az0 = bz[i * 128 + j0], az1 = bz[i * 128 + j1];
    float ar0 = br[i * 128 + j0], ar1 = br[i * 128 + j1];
#pragma unroll 4
    for (int d2 = 0; d2 < 128; ++d2) {
        float x00 = sxt[0][2 * d2], x01 = sxt[0][2 * d2 + 1];
        float x10 = sxt[1][2 * d2], x11 = sxt[1][2 * d2 + 1];
        float w00 = sW[0][2 * d2], w01 = sW[0][2 * d2 + 1];
        float w10 = sW[1][2 * d2], w11 = sW[1][2 * d2 + 1];
        u32 a = WzT[d2 * 256 + i], b = UzT[d2 * 256 + i];
        u32 cc = WrT[d2 * 256 + i], dd = UrT[d2 * 256 + i];
        az0 += blo(a) * x00 + bhi(a) * x01 + blo(b) * w00 + bhi(b) * w01;
        az1 += blo(a) * x10 + bhi(a) * x11 + blo(b) * w10 + bhi(b) * w11;
        ar0 += blo(cc) * x00 + bhi(cc) * x01 + blo(dd) * w00 + bhi(dd) * w01;
        ar1 += blo(cc) * x10 + bhi(cc) * x11 + blo(dd) * w10 + bhi(dd) * w11;
    }
    float z0 = 1.0f / (1.0f + expf(-az0));
    float z1 = 1.0f / (1.0f + expf(-az1));
    float r0 = 1.0f / (1.0f + expf(-ar0));
    float r1 = 1.0f / (1.0f + expf(-ar1));
    srw[0][i] = r0 * wv0;
    srw[1][i] = r1 * wv1;
    __syncthreads();
    float ah0 = bh[i * 128 + j0], ah1 = bh[i * 128 + j1];
#pragma unroll 4
    for (int d2 = 0; d2 < 128; ++d2) {
        float x00 = sxt[0][2 * d2], x01 = sxt[0][2 * d2 + 1];
        float x10 = sxt[1][2 * d2], x11 = sxt[1][2 * d2 + 1];
        float r00 = srw[0][2 * d2], r01 = srw[0][2 * d2 + 1];
        float r10 = srw[1][2 * d2], r11 = srw[1][2 * d2 + 1];
        u32 a = WhT[d2 * 256 + i], b = UhT[d2 * 256 + i];
        ah0 += blo(a) * x00 + bhi(a) * x01 + blo(b) * r00 + bhi(b) * r01;
        ah1 += blo(a) * x10 + bhi(a) * x11 + blo(b) * r10 + bhi(b) * r11;
    }
    float h0 = tanhf(ah0), h1 = tanhf(ah1);
    float wn0 = (1.0f - z0) * wv0 + z0 * h0;
    float wn1 = (1.0f - z1) * wv1 + z1 * h1;
    WnextT[j0 * 256 + i] = wn0;
    WnextT[j1 * 256 + i] = wn1;
    WnT_t[j0 * 256 + i] = f2bf(wn0);
    WnT_t[j1 * 256 + i] = f2bf(wn1);
}

// ---------------- y = x_bf16 @ Wn (MFMA bf16), batched over t ----------------
__global__ __launch_bounds__(128) void k_gemm(const u16* xb16, const u16* WnT, u16* y) {
    int t = blockIdx.y;
    const u16* xb = xb16 + (size_t)t * N_ * DIN;
    const u16* Bt = WnT + t * (DIN * DOUT);
    u16* yb = y + (size_t)t * N_ * DOUT;
    int wid = threadIdx.x >> 6, lane = threadIdx.x & 63;
    int quad = lane >> 4, lm = lane & 15;
    int rowBase = blockIdx.x * 64 + wid * 32;
    f32x4 acc[2][8];
#pragma unroll
    for (int mi = 0; mi < 2; ++mi)
#pragma unroll
        for (int ni = 0; ni < 8; ++ni) acc[mi][ni] = (f32x4){0.f, 0.f, 0.f, 0.f};
    size_t aoff[2];
#pragma unroll
    for (int mi = 0; mi < 2; ++mi) {
        int r = rowBase + mi * 16 + lm;
        if (r > N_ - 1) r = N_ - 1;
        aoff[mi] = (size_t)r * DIN + quad * 8;
    }
    const u16* bbase = Bt + lm * 256 + quad * 8;
    for (int kk = 0; kk < 256; kk += 32) {
        short8 a0 = *(const short8*)(xb + aoff[0] + kk);
        short8 a1 = *(const short8*)(xb + aoff[1] + kk);
#pragma unroll
        for (int ni = 0; ni < 8; ++ni) {
            short8 b = *(const short8*)(bbase + ni * 4096 + kk);
            acc[0][ni] = __builtin_amdgcn_mfma_f32_16x16x32_bf16(a0, b, acc[0][ni], 0, 0, 0);
            acc[1][ni] = __builtin_amdgcn_mfma_f32_16x16x32_bf16(a1, b, acc[1][ni], 0, 0, 0);
        }
    }
#pragma unroll
    for (int mi = 0; mi < 2; ++mi)
#pragma unroll
        for (int ni = 0; ni < 8; ++ni)
#pragma unroll
            for (int r = 0; r < 4; ++r) {
                int row = rowBase + mi * 16 + quad * 4 + r;
                if (row < N_) yb[(size_t)row * DOUT + ni * 16 + lm] = f2bf(acc[mi][ni][r]);
            }
}

// ---------------- CSR gather-aggregate: 4 edges in flight per wave ----------------
__global__ __launch_bounds__(256) void k_agg(const int* offsets, const uint2* srcw,
                                             const u16* y, float* out) {
    int g = blockIdx.x * 4 + (threadIdx.x >> 6);   // < NT
    int lane = threadIdx.x & 63;
    int q = lane >> 4, lq = lane & 15;
    int o0 = offsets[g], o1 = offsets[g + 1];
    float acc[8];
#pragma unroll
    for (int i = 0; i < 8; ++i) acc[i] = 0.f;
    for (int e0 = o0; e0 < o1; e0 += 4) {
        int e = e0 + q;
        if (e < o1) {
            uint2 m = srcw[e];
            float wv = __uint_as_float(m.y);
            uint4 v = *(const uint4*)(y + (size_t)m.x * DOUT + lq * 8);
            acc[0] += wv * blo(v.x); acc[1] += wv * bhi(v.x);
            acc[2] += wv * blo(v.y); acc[3] += wv * bhi(v.y);
            acc[4] += wv * blo(v.z); acc[5] += wv * bhi(v.z);
            acc[6] += wv * blo(v.w); acc[7] += wv * bhi(v.w);
        }
    }
#pragma unroll
    for (int i = 0; i < 8; ++i) {
        acc[i] += __shfl_xor(acc[i], 16);
        acc[i] += __shfl_xor(acc[i], 32);
        acc[i] = (acc[i] >= 0.f) ? acc[i] : SLOPE * acc[i];
    }
    if (q == 0) {
        float4 v0 = make_float4(acc[0], acc[1], acc[2], acc[3]);
        float4 v1 = make_float4(acc[4], acc[5], acc[6], acc[7]);
        float* ob = out + (size_t)g * DOUT + lq * 8;
        *(float4*)ob = v0;
        *(float4*)(ob + 4) = v1;
    }
}

extern "C" void kernel_launch(void* const* d_in, const int* in_sizes, int n_in,
                              void* d_out, int out_size, void* d_ws, size_t ws_size,
                              hipStream_t stream) {
    const float* x = (const float*)d_in[0];
    const int* ei = (const int*)d_in[1];
    const float* ew = (const float*)d_in[2];
    const float* mask = (const float*)d_in[3];
    const float* p = (const float*)d_in[4];
    const float* Wz = (const float*)d_in[5];
    const float* Uz = (const float*)d_in[6];
    const float* bz = (const float*)d_in[7];
    const float* Wr = (const float*)d_in[8];
    const float* Ur = (const float*)d_in[9];
    const float* br = (const float*)d_in[10];
    const float* Wh = (const float*)d_in[11];
    const float* Uh = (const float*)d_in[12];
    const float* bh = (const float*)d_in[13];
    const float* W0 = (const float*)d_in[14];
    float* out = (float*)d_out;

    char* w = (char*)d_ws;
    u16* xb16 = (u16*)w;        w += (size_t)NT * DIN * 2;   // 40,960,000
    float* scores = (float*)w;  w += 320256;                 // NT f32
    float* xtT = (float*)w;     w += 4 * 32768 * 4;          // [t][128][256] f32
    float* Wst = (float*)w;     w += 2 * 32768 * 4;          // ping-pong W^T state f32
    u16* WnT = (u16*)w;         w += 4 * 32768 * 2;          // [t][128][256] bf16
    u32* Tp = (u32*)w;          w += 6 * 32768 * 4;          // packed transposed weights
    u16* y = (u16*)w;           w += (size_t)NT * DOUT * 2;  // [t][N][128] bf16
    int* counts = (int*)w;      w += 320000;
    int* cursor = (int*)w;      w += 320000;                 // adjacent to counts
    int* offsets = (int*)w;     w += 320256;                 // NT+1
    int* blkSum = (int*)w;      w += 2048;
    int* blkOff = (int*)w;      w += 2048;
    uint2* srcw = (uint2*)w;    w += (size_t)TE * 8;

    hipMemsetAsync(counts, 0, 640000, stream);  // counts + cursor

    k_transpose<<<768, 256, 0, stream>>>(Wz, Uz, Wr, Ur, Wh, Uh, Tp);
    k_scores<<<5000, 256, 0, stream>>>(x, p, mask, scores, xb16);
    k_count<<<TE / 256, 256, 0, stream>>>(ei, counts);
    k_scan1<<<313, 256, 0, stream>>>(counts, offsets, blkSum);
    k_scan2<<<1, 64, 0, stream>>>(blkSum, blkOff, offsets);
    k_scan3<<<313, 256, 0, stream>>>(offsets, blkOff);
    k_place<<<TE / 256, 256, 0, stream>>>(ei, ew, offsets, cursor, srcw);
    k_topk<<<4, 1024, 0, stream>>>(scores, x, xtT);

    for (int t = 0; t < 4; ++t) {
        const float* WprevT = (t == 0) ? Wst : (Wst + ((t + 1) & 1) * 32768);
        float* WnextT = Wst + (t & 1) * 32768;
        k_gru<<<64, 256, 0, stream>>>(xtT + t * 32768, WprevT, W0, (t == 0) ? 1 : 0, Tp,
                                      bz, br, bh, WnextT, WnT + t * 32768);
    }
    k_gemm<<<dim3(313, 4), 128, 0, stream>>>(xb16, WnT, y);
    k_agg<<<N_, 256, 0, stream>>>(offsets, srcw, y, out);
}

// Round 4
// 636.517 us; speedup vs baseline: 1.3623x; 1.0442x over previous
//
#include <hip/hip_runtime.h>

typedef unsigned short u16;
typedef unsigned int u32;
typedef unsigned long long u64;

#define T_ 4
#define N_ 20000
#define E_ 640000
#define DIN 256
#define DOUT 128
#define NT (T_*N_)          // 80000
#define TE (T_*E_)          // 2560000
#define SLOPE 0.22916666666666666f

typedef __attribute__((ext_vector_type(8))) short short8;
typedef __attribute__((ext_vector_type(4))) float f32x4;

__device__ __forceinline__ float blo(u32 u) { return __uint_as_float(u << 16); }
__device__ __forceinline__ float bhi(u32 u) { return __uint_as_float(u & 0xFFFF0000u); }
__device__ __forceinline__ u16 f2bf(float f) {
    u32 u = __float_as_uint(f);
    return (u16)((u + 0x7FFFu + ((u >> 16) & 1u)) >> 16);
}
__device__ __forceinline__ u32 fkey(float f) {
    u32 u = __float_as_uint(f);
    return (u & 0x80000000u) ? ~u : (u | 0x80000000u);
}
__device__ __forceinline__ float fkeyinv(u32 k) {
    u32 u = (k & 0x80000000u) ? (k ^ 0x80000000u) : ~k;
    return __uint_as_float(u);
}

// ---------------- transpose+pack the 6 GRU weight matrices (f32 -> bf16 pairs) ------
__global__ void k_transpose(const float* Wz, const float* Uz, const float* Wr, const float* Ur,
                            const float* Wh, const float* Uh, u32* Tp) {
    int bid = blockIdx.x;
    int m = bid >> 7, b = bid & 127;
    int idx = b * 256 + threadIdx.x;      // 0..32767
    int d2 = idx & 127, i = idx >> 7;     // coalesced f32 pair reads
    const float* src;
    switch (m) {
        case 0: src = Wz; break;
        case 1: src = Uz; break;
        case 2: src = Wr; break;
        case 3: src = Ur; break;
        case 4: src = Wh; break;
        default: src = Uh; break;
    }
    float lo = src[i * 256 + 2 * d2];
    float hi = src[i * 256 + 2 * d2 + 1];
    Tp[m * 32768 + d2 * 256 + i] = (u32)f2bf(lo) | ((u32)f2bf(hi) << 16);
}

// ---------------- scores: (x.p)/||p|| + mask, plus x -> bf16 conversion ----------------
__global__ __launch_bounds__(256) void k_scores(const float* x, const float* p, const float* mask,
                                                float* scores, u16* xb16) {
    __shared__ float pl[256];
    __shared__ float s_invn;
    int tid = threadIdx.x;
    pl[tid] = p[tid];
    __syncthreads();
    if (tid < 64) {
        float v = pl[tid] * pl[tid] + pl[tid + 64] * pl[tid + 64] +
                  pl[tid + 128] * pl[tid + 128] + pl[tid + 192] * pl[tid + 192];
        for (int o = 32; o > 0; o >>= 1) v += __shfl_xor(v, o);
        if (tid == 0) s_invn = 1.0f / sqrtf(v);
    }
    __syncthreads();
    int wid = tid >> 6, lane = tid & 63;
    for (int it = 0; it < 4; ++it) {
        int node = blockIdx.x * 16 + wid * 4 + it;   // 5000*16 == 80000
        const float* row = x + (size_t)node * DIN + lane * 4;
        float4 u = *(const float4*)row;
        float d = u.x * pl[lane * 4 + 0] + u.y * pl[lane * 4 + 1] +
                  u.z * pl[lane * 4 + 2] + u.w * pl[lane * 4 + 3];
        u32 p0 = (u32)f2bf(u.x) | ((u32)f2bf(u.y) << 16);
        u32 p1 = (u32)f2bf(u.z) | ((u32)f2bf(u.w) << 16);
        *(uint2*)(xb16 + (size_t)node * DIN + lane * 4) = make_uint2(p0, p1);
        for (int o = 32; o > 0; o >>= 1) d += __shfl_xor(d, o);
        if (lane == 0) scores[node] = d * s_invn + mask[node];
    }
}

// ---------------- CSR build: 4 edges per thread for latency overlap ----------------
__global__ __launch_bounds__(256) void k_count(const int* ei, int* counts) {
    int base = blockIdx.x * 1024 + threadIdx.x;
#pragma unroll
    for (int p = 0; p < 4; ++p) {
        int e = base + p * 256;                      // < TE exactly
        int t = e / E_;
        int l = e - t * E_;
        int dst = ei[t * (2 * E_) + l];
        atomicAdd(&counts[t * N_ + dst], 1);
    }
}

__global__ __launch_bounds__(256) void k_scan1(const int* counts, int* offsets, int* blkSum) {
    int tid = threadIdx.x;
    int i = blockIdx.x * 256 + tid;
    int v = (i < NT) ? counts[i] : 0;
    int lane = tid & 63, wid = tid >> 6;
    int x = v;
    for (int o = 1; o < 64; o <<= 1) {
        int y = __shfl_up(x, o);
        if (lane >= o) x += y;
    }
    __shared__ int wtot[4];
    if (lane == 63) wtot[wid] = x;
    __syncthreads();
    int wpre = 0;
    for (int w = 0; w < wid; ++w) wpre += wtot[w];
    if (i < NT) offsets[i] = wpre + x - v;
    if (tid == 255) blkSum[blockIdx.x] = wpre + x;
}

__global__ void k_scan2(const int* blkSum, int* blkOff, int* offsets) {
    int lane = threadIdx.x;   // 64 threads, 1 wave
    int carry = 0;
    for (int base = 0; base < 313; base += 64) {
        int id = base + lane;
        int v = (id < 313) ? blkSum[id] : 0;
        int x = v;
        for (int o = 1; o < 64; o <<= 1) {
            int y = __shfl_up(x, o);
            if (lane >= o) x += y;
        }
        if (id < 313) blkOff[id] = carry + x - v;
        carry += __shfl(x, 63);
    }
    if (lane == 0) offsets[NT] = carry;   // == TE
}

__global__ void k_scan3(int* offsets, const int* blkOff) {
    int i = blockIdx.x * 256 + threadIdx.x;
    if (i < NT) offsets[i] += blkOff[blockIdx.x];
}

__global__ __launch_bounds__(256) void k_place(const int* ei, const float* ew, const int* offsets,
                                               int* cursor, uint2* srcw) {
    int base = blockIdx.x * 1024 + threadIdx.x;
    int g[4], src[4];
    float wv[4];
#pragma unroll
    for (int p = 0; p < 4; ++p) {
        int e = base + p * 256;                      // < TE exactly
        int t = e / E_;
        int l = e - t * E_;
        g[p] = t * N_ + ei[t * (2 * E_) + l];
        src[p] = t * N_ + ei[t * (2 * E_) + E_ + l];
        wv[p] = ew[t * E_ + l];
    }
    int pos[4], off[4];
#pragma unroll
    for (int p = 0; p < 4; ++p) {
        pos[p] = atomicAdd(&cursor[g[p]], 1);
        off[p] = offsets[g[p]];
    }
#pragma unroll
    for (int p = 0; p < 4; ++p)
        srcw[off[p] + pos[p]] = make_uint2((u32)src[p], __float_as_uint(wv[p]));
}

// ---------------- top-128 (radix select, exact jax order) + xtT build ----------------
// keys register-cached: one global pass instead of five
__global__ __launch_bounds__(1024) void k_topk(const float* scores, const float* x, float* xtT) {
    int t = blockIdx.x;
    int tid = threadIdx.x;   // 0..1023
    const float* sc = scores + t * N_;
    __shared__ u32 hist[256];
    __shared__ u32 sh_dig, sh_need;
    __shared__ u64 sel[256];
    __shared__ u32 selCount;
    __shared__ u32 idxl[128];
    __shared__ float tvl[128];

    u32 kreg[20];
#pragma unroll
    for (int p = 0; p < 20; ++p) {
        int i = tid + p * 1024;
        kreg[p] = (i < N_) ? fkey(sc[i]) : 0u;
    }

    u32 pref = 0;
    u32 need = 128;
    for (int pass = 0; pass < 4; ++pass) {
        int shift = 24 - 8 * pass;
        if (tid < 256) hist[tid] = 0;
        __syncthreads();
#pragma unroll
        for (int p = 0; p < 20; ++p) {
            int i = tid + p * 1024;
            u32 k = kreg[p];
            bool ok = (i < N_) && ((pass == 0) || ((k >> (shift + 8)) == pref));
            if (ok) atomicAdd(&hist[(k >> shift) & 255u], 1u);
        }
        __syncthreads();
        if (tid < 64) {
            int l = tid;
            u32 s = hist[4 * l] + hist[4 * l + 1] + hist[4 * l + 2] + hist[4 * l + 3];
            u32 S = s;
            for (int o = 1; o < 64; o <<= 1) {
                u32 y = __shfl_down(S, o);
                if (l + o < 64) S += y;
            }
            u64 m = __ballot(S >= need);
            int L = 63 - __builtin_clzll(m);
            if (l == L) {
                u32 Snext = S - s;
                u32 r = 0;
                for (int dd = 3; dd >= 0; --dd) {
                    u32 hb = hist[4 * L + dd];
                    r += hb;
                    if (Snext + r >= need) {
                        sh_dig = (u32)(4 * L + dd);
                        sh_need = need - (Snext + r - hb);
                        break;
                    }
                }
            }
        }
        __syncthreads();
        pref = (pref << 8) | sh_dig;
        need = sh_need;
        __syncthreads();
    }
    if (tid == 0) selCount = 0;
    __syncthreads();
    u32 theta = pref;
#pragma unroll
    for (int p = 0; p < 20; ++p) {
        int i = tid + p * 1024;
        u32 k = kreg[p];
        if (i < N_ && k >= theta) {
            u32 pos = atomicAdd(&selCount, 1u);
            if (pos < 256) sel[pos] = (((u64)(k ^ 0xFFFFFFFFu)) << 32) | (u32)i;
        }
    }
    __syncthreads();
    u32 c = selCount;
    if (c > 256) c = 256;
    if (tid < 256 && (u32)tid >= c) sel[tid] = 0xFFFFFFFFFFFFFFFFull;
    __syncthreads();
    // bitonic ascending sort: key = (~fkey)<<32 | idx  -> value desc, idx asc
    for (int k2 = 2; k2 <= 256; k2 <<= 1) {
        for (int jj = k2 >> 1; jj > 0; jj >>= 1) {
            if (tid < 256) {
                int i = tid, ixj = i ^ jj;
                if (ixj > i) {
                    u64 A = sel[i], B = sel[ixj];
                    bool asc = ((i & k2) == 0);
                    bool sw = asc ? (A > B) : (A < B);
                    if (sw) { sel[i] = B; sel[ixj] = A; }
                }
            }
            __syncthreads();
        }
    }
    if (tid < 128) {
        u64 v = sel[tid];
        u32 k = ((u32)(v >> 32)) ^ 0xFFFFFFFFu;
        idxl[tid] = (u32)(v & 0xFFFFFFFFu);
        tvl[tid] = tanhf(fkeyinv(k));
    }
    __syncthreads();
    float* xt_t = xtT + t * (DIN * DOUT);
    const float* xb = x + (size_t)t * N_ * DIN;
    for (int e2 = tid; e2 < DIN * DOUT; e2 += 1024) {
        int j = e2 >> 8, d = e2 & 255;
        xt_t[e2] = xb[(size_t)idxl[j] * DIN + d] * tvl[j];
    }
}

// ---------------- fused matrix-GRU: one block per 2 output columns (j0, j0+64) -------
__global__ __launch_bounds__(256) void k_gru(const float* xtT, const float* WprevT,
                                             const float* W0, int firstT, const u32* Tp,
                                             const float* bz, const float* br, const float* bh,
                                             float* WnextT, u16* WnT_t) {
    int j0 = blockIdx.x;          // 0..63
    int j1 = j0 + 64;
    int i = threadIdx.x;          // 0..255
    __shared__ float sxt[2][256], sW[2][256], srw[2][256];
    sxt[0][i] = xtT[j0 * 256 + i];
    sxt[1][i] = xtT[j1 * 256 + i];
    float wv0 = firstT ? W0[i * 128 + j0] : WprevT[j0 * 256 + i];
    float wv1 = firstT ? W0[i * 128 + j1] : WprevT[j1 * 256 + i];
    sW[0][i] = wv0;
    sW[1][i] = wv1;
    __syncthreads();
    const u32* WzT = Tp;
    const u32* UzT = Tp + 32768;
    const u32* WrT = Tp + 65536;
    const u32* UrT = Tp + 98304;
    const u32* WhT = Tp + 131072;
    const u32* UhT = Tp + 163840;
    float az0 = bz[i * 128 + j0], az1 = bz[i * 128 + j1];
    float ar0 = br[i * 128 + j0], ar1 = br[i * 128 + j1];
#pragma unroll 4
    for (int d2 = 0; d2 < 128; ++d2) {
        float x00 = sxt[0][2 * d2], x01 = sxt[0][2 * d2 + 1];
        float x10 = sxt[1][2 * d2], x11 = sxt[1][2 * d2 + 1];
        float w00 = sW[0][2 * d2], w01 = sW[0][2 * d2 + 1];
        float w10 = sW[1][2 * d2], w11 = sW[1][2 * d2 + 1];
        u32 a = WzT[d2 * 256 + i], b = UzT[d2 * 256 + i];
        u32 cc = WrT[d2 * 256 + i], dd = UrT[d2 * 256 + i];
        az0 += blo(a) * x00 + bhi(a) * x01 + blo(b) * w00 + bhi(b) * w01;
        az1 += blo(a) * x10 + bhi(a) * x11 + blo(b) * w10 + bhi(b) * w11;
        ar0 += blo(cc) * x00 + bhi(cc) * x01 + blo(dd) * w00 + bhi(dd) * w01;
        ar1 += blo(cc) * x10 + bhi(cc) * x11 + blo(dd) * w10 + bhi(dd) * w11;
    }
    float z0 = 1.0f / (1.0f + expf(-az0));
    float z1 = 1.0f / (1.0f + expf(-az1));
    float r0 = 1.0f / (1.0f + expf(-ar0));
    float r1 = 1.0f / (1.0f + expf(-ar1));
    srw[0][i] = r0 * wv0;
    srw[1][i] = r1 * wv1;
    __syncthreads();
    float ah0 = bh[i * 128 + j0], ah1 = bh[i * 128 + j1];
#pragma unroll 4
    for (int d2 = 0; d2 < 128; ++d2) {
        float x00 = sxt[0][2 * d2], x01 = sxt[0][2 * d2 + 1];
        float x10 = sxt[1][2 * d2], x11 = sxt[1][2 * d2 + 1];
        float r00 = srw[0][2 * d2], r01 = srw[0][2 * d2 + 1];
        float r10 = srw[1][2 * d2], r11 = srw[1][2 * d2 + 1];
        u32 a = WhT[d2 * 256 + i], b = UhT[d2 * 256 + i];
        ah0 += blo(a) * x00 + bhi(a) * x01 + blo(b) * r00 + bhi(b) * r01;
        ah1 += blo(a) * x10 + bhi(a) * x11 + blo(b) * r10 + bhi(b) * r11;
    }
    float h0 = tanhf(ah0), h1 = tanhf(ah1);
    float wn0 = (1.0f - z0) * wv0 + z0 * h0;
    float wn1 = (1.0f - z1) * wv1 + z1 * h1;
    WnextT[j0 * 256 + i] = wn0;
    WnextT[j1 * 256 + i] = wn1;
    WnT_t[j0 * 256 + i] = f2bf(wn0);
    WnT_t[j1 * 256 + i] = f2bf(wn1);
}

// ---------------- y = x_bf16 @ Wn (MFMA bf16), batched over t ----------------
__global__ __launch_bounds__(128) void k_gemm(const u16* xb16, const u16* WnT, u16* y) {
    int t = blockIdx.y;
    const u16* xb = xb16 + (size_t)t * N_ * DIN;
    const u16* Bt = WnT + t * (DIN * DOUT);
    u16* yb = y + (size_t)t * N_ * DOUT;
    int wid = threadIdx.x >> 6, lane = threadIdx.x & 63;
    int quad = lane >> 4, lm = lane & 15;
    int rowBase = blockIdx.x * 64 + wid * 32;
    f32x4 acc[2][8];
#pragma unroll
    for (int mi = 0; mi < 2; ++mi)
#pragma unroll
        for (int ni = 0; ni < 8; ++ni) acc[mi][ni] = (f32x4){0.f, 0.f, 0.f, 0.f};
    size_t aoff[2];
#pragma unroll
    for (int mi = 0; mi < 2; ++mi) {
        int r = rowBase + mi * 16 + lm;
        if (r > N_ - 1) r = N_ - 1;
        aoff[mi] = (size_t)r * DIN + quad * 8;
    }
    const u16* bbase = Bt + lm * 256 + quad * 8;
    for (int kk = 0; kk < 256; kk += 32) {
        short8 a0 = *(const short8*)(xb + aoff[0] + kk);
        short8 a1 = *(const short8*)(xb + aoff[1] + kk);
#pragma unroll
        for (int ni = 0; ni < 8; ++ni) {
            short8 b = *(const short8*)(bbase + ni * 4096 + kk);
            acc[0][ni] = __builtin_amdgcn_mfma_f32_16x16x32_bf16(a0, b, acc[0][ni], 0, 0, 0);
            acc[1][ni] = __builtin_amdgcn_mfma_f32_16x16x32_bf16(a1, b, acc[1][ni], 0, 0, 0);
        }
    }
#pragma unroll
    for (int mi = 0; mi < 2; ++mi)
#pragma unroll
        for (int ni = 0; ni < 8; ++ni)
#pragma unroll
            for (int r = 0; r < 4; ++r) {
                int row = rowBase + mi * 16 + quad * 4 + r;
                if (row < N_) yb[(size_t)row * DOUT + ni * 16 + lm] = f2bf(acc[mi][ni][r]);
            }
}

// ---------------- CSR gather-aggregate: 8 edges in flight per wave ----------------
__global__ __launch_bounds__(256) void k_agg(const int* offsets, const uint2* srcw,
                                             const u16* y, float* out) {
    int g = blockIdx.x * 4 + (threadIdx.x >> 6);   // < NT
    int lane = threadIdx.x & 63;
    int q = lane >> 4, lq = lane & 15;
    int o0 = offsets[g], o1 = offsets[g + 1];
    float acc[8];
#pragma unroll
    for (int i = 0; i < 8; ++i) acc[i] = 0.f;
    int e0 = o0;
    for (; e0 + 8 <= o1; e0 += 8) {
        int ea = e0 + q, eb = e0 + 4 + q;
        uint2 ma = srcw[ea];
        uint2 mb = srcw[eb];
        float wa = __uint_as_float(ma.y);
        float wb = __uint_as_float(mb.y);
        uint4 va = *(const uint4*)(y + (size_t)ma.x * DOUT + lq * 8);
        uint4 vb = *(const uint4*)(y + (size_t)mb.x * DOUT + lq * 8);
        acc[0] += wa * blo(va.x); acc[1] += wa * bhi(va.x);
        acc[2] += wa * blo(va.y); acc[3] += wa * bhi(va.y);
        acc[4] += wa * blo(va.z); acc[5] += wa * bhi(va.z);
        acc[6] += wa * blo(va.w); acc[7] += wa * bhi(va.w);
        acc[0] += wb * blo(vb.x); acc[1] += wb * bhi(vb.x);
        acc[2] += wb * blo(vb.y); acc[3] += wb * bhi(vb.y);
        acc[4] += wb * blo(vb.z); acc[5] += wb * bhi(vb.z);
        acc[6] += wb * blo(vb.w); acc[7] += wb * bhi(vb.w);
    }
    for (; e0 < o1; e0 += 4) {
        int e = e0 + q;
        if (e < o1) {
            uint2 m = srcw[e];
            float wv = __uint_as_float(m.y);
            uint4 v = *(const uint4*)(y + (size_t)m.x * DOUT + lq * 8);
            acc[0] += wv * blo(v.x); acc[1] += wv * bhi(v.x);
            acc[2] += wv * blo(v.y); acc[3] += wv * bhi(v.y);
            acc[4] += wv * blo(v.z); acc[5] += wv * bhi(v.z);
            acc[6] += wv * blo(v.w); acc[7] += wv * bhi(v.w);
        }
    }
#pragma unroll
    for (int i = 0; i < 8; ++i) {
        acc[i] += __shfl_xor(acc[i], 16);
        acc[i] += __shfl_xor(acc[i], 32);
        acc[i] = (acc[i] >= 0.f) ? acc[i] : SLOPE * acc[i];
    }
    if (q == 0) {
        float4 v0 = make_float4(acc[0], acc[1], acc[2], acc[3]);
        float4 v1 = make_float4(acc[4], acc[5], acc[6], acc[7]);
        float* ob = out + (size_t)g * DOUT + lq * 8;
        *(float4*)ob = v0;
        *(float4*)(ob + 4) = v1;
    }
}

extern "C" void kernel_launch(void* const* d_in, const int* in_sizes, int n_in,
                              void* d_out, int out_size, void* d_ws, size_t ws_size,
                              hipStream_t stream) {
    const float* x = (const float*)d_in[0];
    const int* ei = (const int*)d_in[1];
    const float* ew = (const float*)d_in[2];
    const float* mask = (const float*)d_in[3];
    const float* p = (const float*)d_in[4];
    const float* Wz = (const float*)d_in[5];
    const float* Uz = (const float*)d_in[6];
    const float* bz = (const float*)d_in[7];
    const float* Wr = (const float*)d_in[8];
    const float* Ur = (const float*)d_in[9];
    const float* br = (const float*)d_in[10];
    const float* Wh = (const float*)d_in[11];
    const float* Uh = (const float*)d_in[12];
    const float* bh = (const float*)d_in[13];
    const float* W0 = (const float*)d_in[14];
    float* out = (float*)d_out;

    char* w = (char*)d_ws;
    u16* xb16 = (u16*)w;        w += (size_t)NT * DIN * 2;   // 40,960,000
    float* scores = (float*)w;  w += 320256;                 // NT f32
    float* xtT = (float*)w;     w += 4 * 32768 * 4;          // [t][128][256] f32
    float* Wst = (float*)w;     w += 2 * 32768 * 4;          // ping-pong W^T state f32
    u16* WnT = (u16*)w;         w += 4 * 32768 * 2;          // [t][128][256] bf16
    u32* Tp = (u32*)w;          w += 6 * 32768 * 4;          // packed transposed weights
    u16* y = (u16*)w;           w += (size_t)NT * DOUT * 2;  // [t][N][128] bf16
    int* counts = (int*)w;      w += 320000;
    int* cursor = (int*)w;      w += 320000;                 // adjacent to counts
    int* offsets = (int*)w;     w += 320256;                 // NT+1
    int* blkSum = (int*)w;      w += 2048;
    int* blkOff = (int*)w;      w += 2048;
    uint2* srcw = (uint2*)w;    w += (size_t)TE * 8;

    hipMemsetAsync(counts, 0, 640000, stream);  // counts + cursor

    k_transpose<<<768, 256, 0, stream>>>(Wz, Uz, Wr, Ur, Wh, Uh, Tp);
    k_scores<<<5000, 256, 0, stream>>>(x, p, mask, scores, xb16);
    k_count<<<TE / 1024, 256, 0, stream>>>(ei, counts);
    k_scan1<<<313, 256, 0, stream>>>(counts, offsets, blkSum);
    k_scan2<<<1, 64, 0, stream>>>(blkSum, blkOff, offsets);
    k_scan3<<<313, 256, 0, stream>>>(offsets, blkOff);
    k_place<<<TE / 1024, 256, 0, stream>>>(ei, ew, offsets, cursor, srcw);
    k_topk<<<4, 1024, 0, stream>>>(scores, x, xtT);

    for (int t = 0; t < 4; ++t) {
        const float* WprevT = (t == 0) ? Wst : (Wst + ((t + 1) & 1) * 32768);
        float* WnextT = Wst + (t & 1) * 32768;
        k_gru<<<64, 256, 0, stream>>>(xtT + t * 32768, WprevT, W0, (t == 0) ? 1 : 0, Tp,
                                      bz, br, bh, WnextT, WnT + t * 32768);
    }
    k_gemm<<<dim3(313, 4), 128, 0, stream>>>(xb16, WnT, y);
    k_agg<<<N_, 256, 0, stream>>>(offsets, srcw, y, out);
}